// Round 11
// baseline (82.853 us; speedup 1.0000x reference)
//
#include <hip/hip_runtime.h>

#define N 8192
#define KD 128
#define NCLS 10
#define GRID 512
#define TPB 256

typedef __attribute__((ext_vector_type(4))) int intx4;

// i8 fragment layout (K=64 per MFMA, two ks halves per K=128 row):
//   byte addr = idx16*2048 + ks*1024 + quad*256 + l16*16 + j   (k = ks*64+quad*16+j)
// Q holds rn(30*F) as i8; logit = (qa . qb) / 90.
//
// r11 coherence scheme: phase-1a producers use PLAIN stores (write-combined,
// dirty in the producing XCD's L2) — r5-r10's relaxed-agent atomic stores were
// ~1M individually-serviced 4B ops at the MALL (~25-30us serial tail; the
// pinned ~30us k_fused floor). After the global arrival tree confirms all 1a
// stores are retired in L2s, ONE ELECTED BLOCK PER XCD (s_getreg XCC_ID,
// HW-verified m09) runs __threadfence() = buffer_wbl2+inv for its whole L2 —
// 8 fences total (r4's mistake was 1024). Consumers cache-read Q/diag10/Dpart
// after the wb flag (first touch -> MALL -> fresh). PS/S_rep/cnt_rep keep
// MALL-atomic produce + ld_agent consume. Tree epochs: 1=arrival, 2=wb done,
// 3=barrier 2.

__device__ __forceinline__ float slabmin(const int* __restrict__ Dpart, int slab) {
    float a = fminf(__int_as_float(Dpart[slab * 4 + 0]), __int_as_float(Dpart[slab * 4 + 1]));
    float b = fminf(__int_as_float(Dpart[slab * 4 + 2]), __int_as_float(Dpart[slab * 4 + 3]));
    return fminf(a, b);
}

__device__ __forceinline__ void st_agent(int* p, int v) {
    __hip_atomic_store(p, v, __ATOMIC_RELAXED, __HIP_MEMORY_SCOPE_AGENT);
}
__device__ __forceinline__ float ld_agent_f(const float* p) {
    return __hip_atomic_load(p, __ATOMIC_RELAXED, __HIP_MEMORY_SCOPE_AGENT);
}
__device__ __forceinline__ int ld_agent(const int* p) {
    return __hip_atomic_load(p, __ATOMIC_RELAXED, __HIP_MEMORY_SCOPE_AGENT);
}
__device__ __forceinline__ int fadd_agent(int* p) {
    return __hip_atomic_fetch_add(p, 1, __ATOMIC_RELAXED, __HIP_MEMORY_SCOPE_AGENT);
}

__device__ __forceinline__ void release_flags(int* flagv, int epoch) {
#pragma unroll
    for (int i = 0; i < 8; ++i) st_agent(&flagv[i * 32], epoch);
}
__device__ __forceinline__ void wait_flag(const int* flagv, int b, int epoch) {
    while (ld_agent(&flagv[(b & 7) * 32]) < epoch) __builtin_amdgcn_s_sleep(2);
}
// Tree arrival (thr_grp/thr_root = counter value seen by the LAST arriver).
__device__ __forceinline__ void arrive_tree(int* grp, int* root, int* flagv, int b, int thr_grp,
                                            int thr_root, int epoch) {
    if (fadd_agent(&grp[(b >> 3) * 32]) == thr_grp)
        if (fadd_agent(root) == thr_root) release_flags(flagv, epoch);
}

__global__ __launch_bounds__(TPB, 2) void k_fused(const float* __restrict__ F,
                                                  const int* __restrict__ tgt,
                                                  float* __restrict__ diag10,
                                                  int* __restrict__ Q,
                                                  float* __restrict__ S_rep,
                                                  int* __restrict__ cnt,
                                                  int* __restrict__ cnt_rep,
                                                  float* __restrict__ PS,
                                                  int* __restrict__ Dpart,
                                                  float* __restrict__ accg,
                                                  int* __restrict__ grp,
                                                  int* __restrict__ root,
                                                  int* __restrict__ flagv,
                                                  int* __restrict__ xcdw,
                                                  int* __restrict__ wbdone,
                                                  float* __restrict__ out) {
    const unsigned char* Qb = (const unsigned char*)Q;
    int b = blockIdx.x;
    int t = threadIdx.x;
    int bx = b & 127, y = b >> 7;

    __shared__ int bmin;
    __shared__ union {
        struct { int lh[NCLS]; float red[2][NCLS][KD]; } cls;          // phase 1b (y=2)
        struct { float Ss[NCLS * KD]; int cs[NCLS]; float wsum[4]; } fin; // phase 3 (y=0)
    } sh;

    // ========= Phase 1a: i8 convert, 16 rows per block — PLAIN stores ==========
    {
        int row0 = b * 16;
        if (t == 0) bmin = 0x7f7fffff;       // +3.4e38 bits
        __syncthreads();
        if (t < 16) PS[row0 + t] = 0.f;      // plain; visible after per-XCD wb
        int col4 = t & 31;   // which float4 of the row (k = col4*4)
        int rg = t >> 5;     // 0..7
#pragma unroll
        for (int sw = 0; sw < 2; ++sw) {
            int row = row0 + sw * 8 + rg;
            float4 v = *(const float4*)(F + (size_t)row * KD + col4 * 4);
            float sq = v.x * v.x + v.y * v.y + v.z * v.z + v.w * v.w;
#pragma unroll
            for (int off = 16; off >= 1; off >>= 1) sq += __shfl_xor(sq, off);
            if (col4 == 0) {
                float dg = 10.f * sq;
                diag10[row] = dg;            // plain (one 64B line per block)
                atomicMin(&bmin, __float_as_int(dg));   // LDS atomic, 16/block
            }
            // i8 quantize: q = rn(30*clamp(v, +-4.2))
            int q0 = __float2int_rn(30.f * fminf(fmaxf(v.x, -4.2f), 4.2f));
            int q1 = __float2int_rn(30.f * fminf(fmaxf(v.y, -4.2f), 4.2f));
            int q2 = __float2int_rn(30.f * fminf(fmaxf(v.z, -4.2f), 4.2f));
            int q3 = __float2int_rn(30.f * fminf(fmaxf(v.w, -4.2f), 4.2f));
            int dq = (q0 & 255) | ((q1 & 255) << 8) | ((q2 & 255) << 16) | ((q3 & 255) << 24);
            int idx = (row >> 4) * 512 + (col4 >> 4) * 256 + ((col4 >> 2) & 3) * 64 +
                      (row & 15) * 4 + (col4 & 3);
            Q[idx] = dq;                     // plain, write-combined in L2
        }
        __syncthreads();   // every wave drains vmcnt before s_barrier -> stores in L2
        if (t == 0) {
            Dpart[b] = bmin;                 // plain
            asm volatile("s_waitcnt vmcnt(0)" ::: "memory");
            arrive_tree(grp, root, flagv, b, 7, 63, 1);   // epoch 1: all stores in L2s
        }
    }

    // ====== Phase 1b: class sums (y=2 blocks, 64 rows each) — MALL atomics =====
    if (y == 2) {
        int row0 = bx * 64;
        int k = t & 127, h = t >> 7;
        if (t < NCLS) sh.cls.lh[t] = 0;
        __syncthreads();
        if (t < 64) atomicAdd(&sh.cls.lh[tgt[row0 + t]], 1);
        float local[NCLS];
#pragma unroll
        for (int c = 0; c < NCLS; ++c) local[c] = 0.f;
        for (int ii = 0; ii < 32; ++ii) {
            int row = row0 + h * 32 + ii;
            float v = F[(size_t)row * KD + k];
            int c = tgt[row];
#pragma unroll
            for (int cc = 0; cc < NCLS; ++cc) local[cc] += (cc == c) ? v : 0.f;
        }
#pragma unroll
        for (int cc = 0; cc < NCLS; ++cc) sh.cls.red[h][cc][k] = local[cc];
        __syncthreads();
        if (h == 0) {
            float* srep = S_rep + (bx & 7) * (NCLS * KD);   // 8-way replicas (r10)
#pragma unroll
            for (int cc = 0; cc < NCLS; ++cc)
                atomicAdd(&srep[cc * KD + k], sh.cls.red[0][cc][k] + sh.cls.red[1][cc][k]);
            if (t < NCLS) atomicAdd(&cnt_rep[(bx & 7) * 32 + t], sh.cls.lh[t]);
        }
    }

    // ===== epoch 1 wait, then per-XCD L2 writeback election (8 fences total) ===
    if (t == 0) {
        wait_flag(flagv, b, 1);
        int xcd = __builtin_amdgcn_s_getreg(63508) & 7;   // HW_REG_XCC_ID (m09)
        if (fadd_agent(&xcdw[xcd * 32]) == 0) {
            __threadfence();                 // buffer_wbl2+inv: THIS XCD's L2 -> MALL
            if (fadd_agent(wbdone) == 7) release_flags(flagv, 2);
        }
        wait_flag(flagv, b, 2);              // epoch 2: all 8 XCD L2s written back
    }
    __syncthreads();

    // ================= Phase 2: symmetric-half i8 MFMA pair sweep ==============
    {
        int w = t >> 6, lane = t & 63;
        int quad = lane >> 4, l16 = lane & 15;
        int row0 = bx * 64;
        int nst = (y == 0) ? 5 : ((y == 2) ? 3 : 4);
        bool ext = (y == 1) && (bx < 64) && (w == 0);   // dd=64 tile

        float dmr = slabmin(Dpart, bx);   // row-slab min diag (plain cached, post-wb)

        // A fragments: af[it][ks] for rows row0 + it*16 + l16
        intx4 af[4][2];
#pragma unroll
        for (int it = 0; it < 4; ++it)
#pragma unroll
            for (int ks = 0; ks < 2; ++ks)
                af[it][ks] =
                    *(const intx4*)(Qb + (size_t)(bx * 4 + it) * 2048 + ks * 1024 + lane * 16);

        // double-buffered B fragments
        intx4 bufs[2][4][2];
        {   // prologue: load step 0 (dd = y*16 + w)
            int col0 = ((bx + y * 16 + w) & 127) * 64;
            const unsigned char* bp = Qb + (size_t)(col0 >> 4) * 2048 + lane * 16;
#pragma unroll
            for (int tj = 0; tj < 4; ++tj)
#pragma unroll
                for (int ks = 0; ks < 2; ++ks)
                    bufs[0][tj][ks] = *(const intx4*)(bp + tj * 2048 + ks * 1024);
        }

#pragma unroll
        for (int s = 0; s < 5; ++s) {
            if (s < nst) {
                // prefetch next step's slab (or the ext tile on the last step)
                if (s + 1 < nst) {
                    int ddn = (s + 1 < 4) ? (y * 16 + (s + 1) * 4 + w) : (44 + w);
                    int coln = ((bx + ddn) & 127) * 64;
                    const unsigned char* bp = Qb + (size_t)(coln >> 4) * 2048 + lane * 16;
#pragma unroll
                    for (int tj = 0; tj < 4; ++tj)
#pragma unroll
                        for (int ks = 0; ks < 2; ++ks)
                            bufs[(s + 1) & 1][tj][ks] = *(const intx4*)(bp + tj * 2048 + ks * 1024);
                } else if (ext) {
                    int coln = (bx + 64) * 64;
                    const unsigned char* bp = Qb + (size_t)(coln >> 4) * 2048 + lane * 16;
#pragma unroll
                    for (int tj = 0; tj < 4; ++tj)
#pragma unroll
                        for (int ks = 0; ks < 2; ++ks)
                            bufs[0][tj][ks] = *(const intx4*)(bp + tj * 2048 + ks * 1024);
                }

                int dd = (s < 4) ? (y * 16 + s * 4 + w) : (44 + w);
                int csb = (bx + dd) & 127;   // col slab index
                int col0 = csb * 64;
                int thrq = (int)((fminf(dmr, slabmin(Dpart, csb)) - 60.f) * 90.f);

                intx4 acc[4][4];
#pragma unroll
                for (int it = 0; it < 4; ++it)
#pragma unroll
                    for (int tj = 0; tj < 4; ++tj)
                        acc[it][tj] = (intx4){0, 0, 0, 0};
#pragma unroll
                for (int ks = 0; ks < 2; ++ks)
#pragma unroll
                    for (int it = 0; it < 4; ++it)
#pragma unroll
                        for (int tj = 0; tj < 4; ++tj)
                            acc[it][tj] = __builtin_amdgcn_mfma_i32_16x16x64_i8(
                                af[it][ks], bufs[s & 1][tj][ks], acc[it][tj], 0, 0, 0);

                int mx = -2147483647;
#pragma unroll
                for (int it = 0; it < 4; ++it)
#pragma unroll
                    for (int tj = 0; tj < 4; ++tj) {
                        int a01 = max(acc[it][tj][0], acc[it][tj][1]);
                        int a23 = max(acc[it][tj][2], acc[it][tj][3]);
                        mx = max(mx, max(a01, a23));
                    }

                if (__any(mx > thrq)) {
                    bool has_diag = (col0 == row0);   // wave-uniform (dd==0)
                    // row side: exp(l - M_row) into PS[row] (self excluded on diag)
#pragma unroll
                    for (int it = 0; it < 4; ++it)
#pragma unroll
                        for (int r = 0; r < 4; ++r) {
                            int grow = row0 + it * 16 + quad * 4 + r;
                            float Mrow = diag10[grow];
                            float rs = 0.f;
#pragma unroll
                            for (int tj = 0; tj < 4; ++tj) {
                                int gcol = col0 + tj * 16 + l16;
                                float lv = (float)acc[it][tj][r] * (1.f / 90.f);
                                float ev = __expf(lv - Mrow);
                                rs += (grow == gcol) ? 0.f : ev;
                            }
                            rs += __shfl_xor(rs, 1, 16);
                            rs += __shfl_xor(rs, 2, 16);
                            rs += __shfl_xor(rs, 4, 16);
                            rs += __shfl_xor(rs, 8, 16);
                            if (l16 == 0) atomicAdd(&PS[grow], rs);
                        }
                    // col side (off-diag tiles only): exp(l - M_col) into PS[col]
                    if (!has_diag) {
#pragma unroll
                        for (int tj = 0; tj < 4; ++tj) {
                            int gcol = col0 + tj * 16 + l16;
                            float Mcol = diag10[gcol];
                            float cs_ = 0.f;
#pragma unroll
                            for (int it = 0; it < 4; ++it)
#pragma unroll
                                for (int r = 0; r < 4; ++r)
                                    cs_ += __expf((float)acc[it][tj][r] * (1.f / 90.f) - Mcol);
                            cs_ += __shfl_xor(cs_, 16);
                            cs_ += __shfl_xor(cs_, 32);
                            if (quad == 0) atomicAdd(&PS[gcol], cs_);
                        }
                    }
                }
            }
        }

        // dd=64 extra tile (unordered pair {bx, bx+64}), off-diag semantics (y=1)
        if (ext) {
            int col0 = (bx + 64) * 64;
            int thrq = (int)((fminf(dmr, slabmin(Dpart, bx + 64)) - 60.f) * 90.f);
            intx4 acc[4][4];
#pragma unroll
            for (int it = 0; it < 4; ++it)
#pragma unroll
                for (int tj = 0; tj < 4; ++tj)
                    acc[it][tj] = (intx4){0, 0, 0, 0};
#pragma unroll
            for (int ks = 0; ks < 2; ++ks)
#pragma unroll
                for (int it = 0; it < 4; ++it)
#pragma unroll
                    for (int tj = 0; tj < 4; ++tj)
                        acc[it][tj] = __builtin_amdgcn_mfma_i32_16x16x64_i8(
                            af[it][ks], bufs[0][tj][ks], acc[it][tj], 0, 0, 0);

            int mx = -2147483647;
#pragma unroll
            for (int it = 0; it < 4; ++it)
#pragma unroll
                for (int tj = 0; tj < 4; ++tj) {
                    int a01 = max(acc[it][tj][0], acc[it][tj][1]);
                    int a23 = max(acc[it][tj][2], acc[it][tj][3]);
                    mx = max(mx, max(a01, a23));
                }
            if (__any(mx > thrq)) {
#pragma unroll
                for (int it = 0; it < 4; ++it)
#pragma unroll
                    for (int r = 0; r < 4; ++r) {
                        int grow = row0 + it * 16 + quad * 4 + r;
                        float Mrow = diag10[grow];
                        float rs = 0.f;
#pragma unroll
                        for (int tj = 0; tj < 4; ++tj) {
                            float lv = (float)acc[it][tj][r] * (1.f / 90.f);
                            rs += __expf(lv - Mrow);
                        }
                        rs += __shfl_xor(rs, 1, 16);
                        rs += __shfl_xor(rs, 2, 16);
                        rs += __shfl_xor(rs, 4, 16);
                        rs += __shfl_xor(rs, 8, 16);
                        if (l16 == 0) atomicAdd(&PS[grow], rs);
                    }
#pragma unroll
                for (int tj = 0; tj < 4; ++tj) {
                    int gcol = col0 + tj * 16 + l16;
                    float Mcol = diag10[gcol];
                    float cs_ = 0.f;
#pragma unroll
                    for (int it = 0; it < 4; ++it)
#pragma unroll
                        for (int r = 0; r < 4; ++r)
                            cs_ += __expf((float)acc[it][tj][r] * (1.f / 90.f) - Mcol);
                    cs_ += __shfl_xor(cs_, 16);
                    cs_ += __shfl_xor(cs_, 32);
                    if (quad == 0) atomicAdd(&PS[gcol], cs_);
                }
            }
        }
    }

    // ===== barrier 2 (epoch 3): everyone arrives; only y=0 blocks wait =========
    __syncthreads();   // drains each wave's phase-2 PS atomics (and y=2's S/cnt)
    if (t == 0) {
        asm volatile("s_waitcnt vmcnt(0)" ::: "memory");
        arrive_tree(grp, root, flagv, b, 15, 127, 3);
    }
    if (b >= 128) return;

    // ================= Phase 3: posdot + log-term + reduce (blocks 0..127) =====
    {
        // Prefetch barrier-independent data while waiting for the release flag.
        int g = t >> 2, q = t & 3;            // 4 lanes per row
        int row = b * 64 + g;
        int c = tgt[row];
        float4 ff[8];
#pragma unroll
        for (int i = 0; i < 8; ++i)
            ff[i] = *(const float4*)(F + (size_t)row * KD + i * 16 + q * 4);
        float M = diag10[row];

        if (t == 0) wait_flag(flagv, b, 3);
        __syncthreads();

        // Sum the 8 S/cnt replicas with agent-scope (cache-bypass) loads.
        for (int i = t; i < NCLS * KD; i += TPB) {
            float sv = 0.f;
#pragma unroll
            for (int r = 0; r < 8; ++r) sv += ld_agent_f(&S_rep[r * (NCLS * KD) + i]);
            sh.fin.Ss[i] = sv;
        }
        if (t < NCLS) {
            int cv = 0;
#pragma unroll
            for (int r = 0; r < 8; ++r) cv += ld_agent(&cnt_rep[r * 32 + t]);
            sh.fin.cs[t] = cv;
        }
        __syncthreads();

        float dot = 0.f;
#pragma unroll
        for (int i = 0; i < 8; ++i) {
            float4 s = *(const float4*)(sh.fin.Ss + c * KD + i * 16 + q * 4);
            dot += ff[i].x * s.x + ff[i].y * s.y + ff[i].z * s.z + ff[i].w * s.w;
        }
        dot += __shfl_xor(dot, 1, 4);
        dot += __shfl_xor(dot, 2, 4);

        float mlp = 0.f;
        if (q == 0) {
            float pp = 10.f * dot - M;            // sum over positives of logits
            float T = ld_agent_f(&PS[row]);       // surviving shifted exp mass
            float np = (float)(sh.fin.cs[c] - 1);
            mlp = (np < 0.5f) ? 0.f : (pp - np * (M + __logf(T + 1e-20f))) / np;
        }
#pragma unroll
        for (int off = 32; off >= 1; off >>= 1) mlp += __shfl_xor(mlp, off);
        int lane = t & 63, w = t >> 6;
        if (lane == 0) sh.fin.wsum[w] = mlp;
        __syncthreads();
        if (t == 0) {
            atomicAdd(accg, (sh.fin.wsum[0] + sh.fin.wsum[1]) + (sh.fin.wsum[2] + sh.fin.wsum[3]));
            asm volatile("s_waitcnt vmcnt(0)" ::: "memory");   // accg add at MALL before ticket
            int old = atomicAdd(&cnt[12], 1);   // ticket among 128 final blocks
            if (old == 127) {
                float tot = atomicAdd(accg, 0.0f);   // coherent read of total
                double sp = 0.0, sn = 0.0;
                for (int cc = 0; cc < NCLS; ++cc) {
                    double n = (double)sh.fin.cs[cc];
                    sp += n * (n - 1.0);
                    sn += n * ((double)N - n);
                }
                out[0] = (float)(-(0.1 / 0.07) * ((double)tot / (double)N));
                out[1] = (float)(sp / (double)N);
                out[2] = (float)(sn / (double)N);
            }
        }
    }
}

extern "C" void kernel_launch(void* const* d_in, const int* in_sizes, int n_in,
                              void* d_out, int out_size, void* d_ws, size_t ws_size,
                              hipStream_t stream) {
    const float* F = (const float*)d_in[0];
    const int* tgt = (const int*)d_in[1];
    float* out = (float*)d_out;
    char* ws = (char*)d_ws;

    int* cnt = (int*)(ws);                       // 64 B (ticket at cnt[12])
    float* acc = (float*)(ws + 64);              // 4 B
    int* flagv = (int*)(ws + 6144);              // 8 release-flag copies, 128 B apart
    int* root = (int*)(ws + 7168);               // tree root counter (own line)
    float* S_rep = (float*)(ws + 8192);          // 8 replicas x 5120 B = 40 KiB -> 49152
    int* grp = (int*)(ws + 49152);               // 64 group counters, 128 B apart (8 KiB)
    int* cnt_rep = (int*)(ws + 57344);           // 8 replicas x 128 B = 1 KiB
    int* xcdw = (int*)(ws + 58368);              // 8 per-XCD wb tickets, 128 B apart
    int* wbdone = (int*)(ws + 59392);            // wb completion counter (own line)
    float* PS = (float*)(ws + 98304);            // 32 KiB (zeroed in phase 1, plain)
    int* Dpart = (int*)(ws + 131072);            // 2 KiB (per-16-row diag mins)
    float* diag10 = (float*)(ws + 163840);       // 32 KiB
    int* Q = (int*)(ws + (1u << 20));            // 1 MiB (i8 frags of 30*F)

    hipMemsetAsync(ws, 0, 61440, stream);        // cnt+acc+flags+root+S_rep+grp+cnt_rep+xcdw+wbdone
    k_fused<<<GRID, TPB, 0, stream>>>(F, tgt, diag10, Q, S_rep, cnt, cnt_rep, PS, Dpart, acc,
                                      grp, root, flagv, xcdw, wbdone, out);
}

// Round 12
// 80.342 us; speedup vs baseline: 1.0313x; 1.0313x over previous
//
#include <hip/hip_runtime.h>

#define N 8192
#define KD 128
#define NCLS 10
#define GRID 512
#define TPB 256

typedef __attribute__((ext_vector_type(4))) int intx4;

// i8 fragment layout (K=64 per MFMA, two ks halves per K=128 row):
//   byte addr = idx16*2048 + ks*1024 + quad*256 + l16*16 + j   (k = ks*64+quad*16+j)
// Q holds rn(30*F) as i8; logit = (qa . qb) / 90.
//
// r12: ONE dispatch, no memset. All sync state lives in __device__ globals
// (zero at module load, NOT re-poisoned by the harness) using MONOTONE EPOCH
// counters: each counter accrues a fixed count per iteration, so last-arriver
// tests are modulus tests and the iteration index i falls out of the counter
// value. S/cnt accumulators are parity double-buffers (iter i uses i&1, zeros
// (i&1)^1 for the next iter). Loss accumulator -> per-block ws slots (written
// before read each iter; no init). Everything else identical to r10: st_agent
// (MALL write-through) producers for Q/PS/diag10/Dpart; consumers cache-read
// first-touch-after-sync lines or ld_agent for atomically-updated data;
// per-slab ready flags for 1a->2; tree barrier for 2->3.

// -------- persistent sync state (module-lifetime, epoch-based) --------
__device__ int g_grp[64 * 32];      // 64 group ctrs, 128B apart; +16/iter (8 b1 + 8 b2)
__device__ int g_root[32];          // root ctr; +128/iter (64 b1 + 64 b2)
__device__ int g_flag[8 * 32];      // 8 release-flag copies; epoch 2i+1 (b1), 2i+2 (b2)
__device__ int g_slabc[128 * 32];   // per-slab producer ctrs; +4/iter
__device__ int g_slabf[128 * 32];   // per-slab ready flags; epoch i+1
__device__ int g_ticket[32];        // phase-3 ticket; +128/iter
__device__ float g_S[2][8][NCLS * KD];   // parity x 8 replicas (r10)
__device__ int g_cnt[2][8][16];          // parity x 8 replicas

__device__ __forceinline__ float slabmin(const int* __restrict__ Dpart, int slab) {
    float a = fminf(__int_as_float(Dpart[slab * 4 + 0]), __int_as_float(Dpart[slab * 4 + 1]));
    float b = fminf(__int_as_float(Dpart[slab * 4 + 2]), __int_as_float(Dpart[slab * 4 + 3]));
    return fminf(a, b);
}

__device__ __forceinline__ void st_agent(int* p, int v) {
    __hip_atomic_store(p, v, __ATOMIC_RELAXED, __HIP_MEMORY_SCOPE_AGENT);
}
__device__ __forceinline__ void st_agent_f(float* p, float v) {
    __hip_atomic_store(p, v, __ATOMIC_RELAXED, __HIP_MEMORY_SCOPE_AGENT);
}
__device__ __forceinline__ float ld_agent_f(const float* p) {
    return __hip_atomic_load(p, __ATOMIC_RELAXED, __HIP_MEMORY_SCOPE_AGENT);
}
__device__ __forceinline__ int ld_agent(const int* p) {
    return __hip_atomic_load(p, __ATOMIC_RELAXED, __HIP_MEMORY_SCOPE_AGENT);
}
__device__ __forceinline__ int fadd_agent(int* p) {
    return __hip_atomic_fetch_add(p, 1, __ATOMIC_RELAXED, __HIP_MEMORY_SCOPE_AGENT);
}
__device__ __forceinline__ void release_flags(int epoch) {
#pragma unroll
    for (int i = 0; i < 8; ++i) st_agent(&g_flag[i * 32], epoch);
}
__device__ __forceinline__ void wait_flag(int b, int epoch) {
    while (ld_agent(&g_flag[(b & 7) * 32]) < epoch) __builtin_amdgcn_s_sleep(2);
}

__global__ __launch_bounds__(TPB, 2) void k_fused(const float* __restrict__ F,
                                                  const int* __restrict__ tgt,
                                                  float* __restrict__ diag10,
                                                  int* __restrict__ Q,
                                                  float* __restrict__ PS,
                                                  int* __restrict__ Dpart,
                                                  float* __restrict__ wsumv,
                                                  float* __restrict__ out) {
    const unsigned char* Qb = (const unsigned char*)Q;
    int b = blockIdx.x;
    int t = threadIdx.x;
    int bx = b & 127, y = b >> 7;

    __shared__ int bmin;
    __shared__ int sh_iter;
    __shared__ union {
        struct { int lh[NCLS]; float red[2][NCLS][KD]; } cls;          // phase 1b (y=2)
        struct { float Ss[NCLS * KD]; int cs[NCLS]; float wsum[4]; } fin; // phase 3 (y=0)
    } sh;

    // ========= Phase 1a: i8 convert, 16 rows per block (st_agent producers) ====
    {
        int row0 = b * 16;
        if (t == 0) bmin = 0x7f7fffff;       // +3.4e38 bits
        __syncthreads();
        if (t < 16) st_agent_f(&PS[row0 + t], 0.f);
        int col4 = t & 31;   // which float4 of the row (k = col4*4)
        int rg = t >> 5;     // 0..7
#pragma unroll
        for (int sw = 0; sw < 2; ++sw) {
            int row = row0 + sw * 8 + rg;
            float4 v = *(const float4*)(F + (size_t)row * KD + col4 * 4);
            float sq = v.x * v.x + v.y * v.y + v.z * v.z + v.w * v.w;
#pragma unroll
            for (int off = 16; off >= 1; off >>= 1) sq += __shfl_xor(sq, off);
            if (col4 == 0) {
                float dg = 10.f * sq;
                st_agent_f(&diag10[row], dg);
                atomicMin(&bmin, __float_as_int(dg));   // LDS atomic, 16/block
            }
            // i8 quantize: q = rn(30*clamp(v, +-4.2))
            int q0 = __float2int_rn(30.f * fminf(fmaxf(v.x, -4.2f), 4.2f));
            int q1 = __float2int_rn(30.f * fminf(fmaxf(v.y, -4.2f), 4.2f));
            int q2 = __float2int_rn(30.f * fminf(fmaxf(v.z, -4.2f), 4.2f));
            int q3 = __float2int_rn(30.f * fminf(fmaxf(v.w, -4.2f), 4.2f));
            int dq = (q0 & 255) | ((q1 & 255) << 8) | ((q2 & 255) << 16) | ((q3 & 255) << 24);
            int idx = (row >> 4) * 512 + (col4 >> 4) * 256 + ((col4 >> 2) & 3) * 64 +
                      (row & 15) * 4 + (col4 & 3);
            st_agent(&Q[idx], dq);
        }
        __syncthreads();   // all waves' stores drained (waitcnt before s_barrier)
        if (t == 0) {
            st_agent(&Dpart[b], bmin);
            asm volatile("s_waitcnt vmcnt(0)" ::: "memory");
            // per-slab readiness: 4 producers/slab/iter; last sets epoch i+1
            int so = fadd_agent(&g_slabc[(b >> 2) * 32]);
            if ((so & 3) == 3) st_agent(&g_slabf[(b >> 2) * 32], (so >> 2) + 1);
            // barrier-1 tree arrival; group ctr +16/iter -> iter = old>>4
            int go = fadd_agent(&g_grp[(b >> 3) * 32]);
            sh_iter = go >> 4;
            if ((go & 15) == 7) {
                int ro = fadd_agent(&g_root[0]);
                if ((ro & 127) == 63) release_flags(2 * (ro >> 7) + 1);
            }
        }
        __syncthreads();
    }
    int iter = sh_iter;
    int par = iter & 1;

    // ====== Phase 1b: class sums (y=2 blocks, 64 rows each) — parity bufs ======
    if (y == 2) {
        int row0 = bx * 64;
        int k = t & 127, h = t >> 7;
        if (t < NCLS) sh.cls.lh[t] = 0;
        __syncthreads();
        if (t < 64) atomicAdd(&sh.cls.lh[tgt[row0 + t]], 1);
        float local[NCLS];
#pragma unroll
        for (int c = 0; c < NCLS; ++c) local[c] = 0.f;
        for (int ii = 0; ii < 32; ++ii) {
            int row = row0 + h * 32 + ii;
            float v = F[(size_t)row * KD + k];
            int c = tgt[row];
#pragma unroll
            for (int cc = 0; cc < NCLS; ++cc) local[cc] += (cc == c) ? v : 0.f;
        }
#pragma unroll
        for (int cc = 0; cc < NCLS; ++cc) sh.cls.red[h][cc][k] = local[cc];
        __syncthreads();
        if (h == 0) {
            float* srep = &g_S[par][bx & 7][0];   // 8-way replicas (r10)
#pragma unroll
            for (int cc = 0; cc < NCLS; ++cc)
                atomicAdd(&srep[cc * KD + k], sh.cls.red[0][cc][k] + sh.cls.red[1][cc][k]);
            if (t < NCLS) atomicAdd(&g_cnt[par][bx & 7][t], sh.cls.lh[t]);
        }
    }

    // ===== wait for the 13-20 slabs THIS block consumes (per-lane poll) ========
    {
        int dd = -1;
        if (y == 0) {
            if (t < 16) dd = t;                 // dd 0..15 (incl. A slab + diag)
            else if (t < 20) dd = t + 28;       // dd 44..47 (rebalanced steps)
        } else if (y == 1) {
            if (t < 16) dd = 16 + t;            // dd 16..31
            else if (t == 16) dd = 0;           // A slab
            else if (t == 17 && bx < 64) dd = 64;   // ext slab
        } else if (y == 2) {
            if (t < 12) dd = 32 + t;            // dd 32..43
            else if (t == 12) dd = 0;
        } else {
            if (t < 16) dd = 48 + t;            // dd 48..63
            else if (t == 16) dd = 0;
        }
        if (dd >= 0) {
            int s = (bx + dd) & 127;
            while (ld_agent(&g_slabf[s * 32]) < iter + 1) __builtin_amdgcn_s_sleep(2);
        }
        __syncthreads();
    }

    // ================= Phase 2: symmetric-half i8 MFMA pair sweep ==============
    {
        int w = t >> 6, lane = t & 63;
        int quad = lane >> 4, l16 = lane & 15;
        int row0 = bx * 64;
        int nst = (y == 0) ? 5 : ((y == 2) ? 3 : 4);
        bool ext = (y == 1) && (bx < 64) && (w == 0);   // dd=64 tile

        float dmr = slabmin(Dpart, bx);   // row-slab min diag

        // A fragments: af[it][ks] for rows row0 + it*16 + l16
        intx4 af[4][2];
#pragma unroll
        for (int it = 0; it < 4; ++it)
#pragma unroll
            for (int ks = 0; ks < 2; ++ks)
                af[it][ks] =
                    *(const intx4*)(Qb + (size_t)(bx * 4 + it) * 2048 + ks * 1024 + lane * 16);

        // double-buffered B fragments
        intx4 bufs[2][4][2];
        {   // prologue: load step 0 (dd = y*16 + w)
            int col0 = ((bx + y * 16 + w) & 127) * 64;
            const unsigned char* bp = Qb + (size_t)(col0 >> 4) * 2048 + lane * 16;
#pragma unroll
            for (int tj = 0; tj < 4; ++tj)
#pragma unroll
                for (int ks = 0; ks < 2; ++ks)
                    bufs[0][tj][ks] = *(const intx4*)(bp + tj * 2048 + ks * 1024);
        }

#pragma unroll
        for (int s = 0; s < 5; ++s) {
            if (s < nst) {
                // prefetch next step's slab (or the ext tile on the last step)
                if (s + 1 < nst) {
                    int ddn = (s + 1 < 4) ? (y * 16 + (s + 1) * 4 + w) : (44 + w);
                    int coln = ((bx + ddn) & 127) * 64;
                    const unsigned char* bp = Qb + (size_t)(coln >> 4) * 2048 + lane * 16;
#pragma unroll
                    for (int tj = 0; tj < 4; ++tj)
#pragma unroll
                        for (int ks = 0; ks < 2; ++ks)
                            bufs[(s + 1) & 1][tj][ks] = *(const intx4*)(bp + tj * 2048 + ks * 1024);
                } else if (ext) {
                    int coln = (bx + 64) * 64;
                    const unsigned char* bp = Qb + (size_t)(coln >> 4) * 2048 + lane * 16;
#pragma unroll
                    for (int tj = 0; tj < 4; ++tj)
#pragma unroll
                        for (int ks = 0; ks < 2; ++ks)
                            bufs[0][tj][ks] = *(const intx4*)(bp + tj * 2048 + ks * 1024);
                }

                int dd = (s < 4) ? (y * 16 + s * 4 + w) : (44 + w);
                int csb = (bx + dd) & 127;   // col slab index
                int col0 = csb * 64;
                int thrq = (int)((fminf(dmr, slabmin(Dpart, csb)) - 60.f) * 90.f);

                intx4 acc[4][4];
#pragma unroll
                for (int it = 0; it < 4; ++it)
#pragma unroll
                    for (int tj = 0; tj < 4; ++tj)
                        acc[it][tj] = (intx4){0, 0, 0, 0};
#pragma unroll
                for (int ks = 0; ks < 2; ++ks)
#pragma unroll
                    for (int it = 0; it < 4; ++it)
#pragma unroll
                        for (int tj = 0; tj < 4; ++tj)
                            acc[it][tj] = __builtin_amdgcn_mfma_i32_16x16x64_i8(
                                af[it][ks], bufs[s & 1][tj][ks], acc[it][tj], 0, 0, 0);

                int mx = -2147483647;
#pragma unroll
                for (int it = 0; it < 4; ++it)
#pragma unroll
                    for (int tj = 0; tj < 4; ++tj) {
                        int a01 = max(acc[it][tj][0], acc[it][tj][1]);
                        int a23 = max(acc[it][tj][2], acc[it][tj][3]);
                        mx = max(mx, max(a01, a23));
                    }

                if (__any(mx > thrq)) {
                    bool has_diag = (col0 == row0);   // wave-uniform (dd==0)
                    // row side: exp(l - M_row) into PS[row] (self excluded on diag)
#pragma unroll
                    for (int it = 0; it < 4; ++it)
#pragma unroll
                        for (int r = 0; r < 4; ++r) {
                            int grow = row0 + it * 16 + quad * 4 + r;
                            float Mrow = diag10[grow];
                            float rs = 0.f;
#pragma unroll
                            for (int tj = 0; tj < 4; ++tj) {
                                int gcol = col0 + tj * 16 + l16;
                                float lv = (float)acc[it][tj][r] * (1.f / 90.f);
                                float ev = __expf(lv - Mrow);
                                rs += (grow == gcol) ? 0.f : ev;
                            }
                            rs += __shfl_xor(rs, 1, 16);
                            rs += __shfl_xor(rs, 2, 16);
                            rs += __shfl_xor(rs, 4, 16);
                            rs += __shfl_xor(rs, 8, 16);
                            if (l16 == 0) atomicAdd(&PS[grow], rs);
                        }
                    // col side (off-diag tiles only): exp(l - M_col) into PS[col]
                    if (!has_diag) {
#pragma unroll
                        for (int tj = 0; tj < 4; ++tj) {
                            int gcol = col0 + tj * 16 + l16;
                            float Mcol = diag10[gcol];
                            float cs_ = 0.f;
#pragma unroll
                            for (int it = 0; it < 4; ++it)
#pragma unroll
                                for (int r = 0; r < 4; ++r)
                                    cs_ += __expf((float)acc[it][tj][r] * (1.f / 90.f) - Mcol);
                            cs_ += __shfl_xor(cs_, 16);
                            cs_ += __shfl_xor(cs_, 32);
                            if (quad == 0) atomicAdd(&PS[gcol], cs_);
                        }
                    }
                }
            }
        }

        // dd=64 extra tile (unordered pair {bx, bx+64}), off-diag semantics (y=1)
        if (ext) {
            int col0 = (bx + 64) * 64;
            int thrq = (int)((fminf(dmr, slabmin(Dpart, bx + 64)) - 60.f) * 90.f);
            intx4 acc[4][4];
#pragma unroll
            for (int it = 0; it < 4; ++it)
#pragma unroll
                for (int tj = 0; tj < 4; ++tj)
                    acc[it][tj] = (intx4){0, 0, 0, 0};
#pragma unroll
            for (int ks = 0; ks < 2; ++ks)
#pragma unroll
                for (int it = 0; it < 4; ++it)
#pragma unroll
                    for (int tj = 0; tj < 4; ++tj)
                        acc[it][tj] = __builtin_amdgcn_mfma_i32_16x16x64_i8(
                            af[it][ks], bufs[0][tj][ks], acc[it][tj], 0, 0, 0);

            int mx = -2147483647;
#pragma unroll
            for (int it = 0; it < 4; ++it)
#pragma unroll
                for (int tj = 0; tj < 4; ++tj) {
                    int a01 = max(acc[it][tj][0], acc[it][tj][1]);
                    int a23 = max(acc[it][tj][2], acc[it][tj][3]);
                    mx = max(mx, max(a01, a23));
                }
            if (__any(mx > thrq)) {
#pragma unroll
                for (int it = 0; it < 4; ++it)
#pragma unroll
                    for (int r = 0; r < 4; ++r) {
                        int grow = row0 + it * 16 + quad * 4 + r;
                        float Mrow = diag10[grow];
                        float rs = 0.f;
#pragma unroll
                        for (int tj = 0; tj < 4; ++tj) {
                            float lv = (float)acc[it][tj][r] * (1.f / 90.f);
                            rs += __expf(lv - Mrow);
                        }
                        rs += __shfl_xor(rs, 1, 16);
                        rs += __shfl_xor(rs, 2, 16);
                        rs += __shfl_xor(rs, 4, 16);
                        rs += __shfl_xor(rs, 8, 16);
                        if (l16 == 0) atomicAdd(&PS[grow], rs);
                    }
#pragma unroll
                for (int tj = 0; tj < 4; ++tj) {
                    int gcol = col0 + tj * 16 + l16;
                    float Mcol = diag10[gcol];
                    float cs_ = 0.f;
#pragma unroll
                    for (int it = 0; it < 4; ++it)
#pragma unroll
                        for (int r = 0; r < 4; ++r)
                            cs_ += __expf((float)acc[it][tj][r] * (1.f / 90.f) - Mcol);
                    cs_ += __shfl_xor(cs_, 16);
                    cs_ += __shfl_xor(cs_, 32);
                    if (quad == 0) atomicAdd(&PS[gcol], cs_);
                }
            }
        }
    }

    // ===== barrier 2: everyone arrives; only y=0 blocks wait (epoch 2i+2) ======
    __syncthreads();   // drains each wave's phase-2 PS atomics (and y=2's S/cnt)
    if (t == 0) {
        asm volatile("s_waitcnt vmcnt(0)" ::: "memory");
        int go = fadd_agent(&g_grp[(b >> 3) * 32]);
        if ((go & 15) == 15) {
            int ro = fadd_agent(&g_root[0]);
            if ((ro & 127) == 127) release_flags(2 * (ro >> 7) + 2);
        }
    }
    if (b >= 128) return;

    // ================= Phase 3: posdot + log-term + reduce (blocks 0..127) =====
    {
        // Prefetch barrier-independent data while waiting for the release flag.
        int g = t >> 2, q = t & 3;            // 4 lanes per row
        int row = b * 64 + g;
        int c = tgt[row];
        float4 ff[8];
#pragma unroll
        for (int i = 0; i < 8; ++i)
            ff[i] = *(const float4*)(F + (size_t)row * KD + i * 16 + q * 4);
        float M = diag10[row];

        // zero the OTHER parity's S/cnt for the next iteration (untouched this iter)
        if (t < 80) st_agent_f(&(&g_S[par ^ 1][0][0])[b * 80 + t], 0.f);
        if (t == 80) st_agent(&(&g_cnt[par ^ 1][0][0])[b], 0);

        if (t == 0) wait_flag(b, 2 * iter + 2);
        __syncthreads();

        // Sum the 8 S/cnt replicas with agent-scope (cache-bypass) loads.
        for (int i = t; i < NCLS * KD; i += TPB) {
            float sv = 0.f;
#pragma unroll
            for (int r = 0; r < 8; ++r) sv += ld_agent_f(&g_S[par][r][i]);
            sh.fin.Ss[i] = sv;
        }
        if (t < NCLS) {
            int cv = 0;
#pragma unroll
            for (int r = 0; r < 8; ++r) cv += ld_agent(&g_cnt[par][r][t]);
            sh.fin.cs[t] = cv;
        }
        __syncthreads();

        float dot = 0.f;
#pragma unroll
        for (int i = 0; i < 8; ++i) {
            float4 s = *(const float4*)(sh.fin.Ss + c * KD + i * 16 + q * 4);
            dot += ff[i].x * s.x + ff[i].y * s.y + ff[i].z * s.z + ff[i].w * s.w;
        }
        dot += __shfl_xor(dot, 1, 4);
        dot += __shfl_xor(dot, 2, 4);

        float mlp = 0.f;
        if (q == 0) {
            float pp = 10.f * dot - M;            // sum over positives of logits
            float T = ld_agent_f(&PS[row]);       // surviving shifted exp mass
            float np = (float)(sh.fin.cs[c] - 1);
            mlp = (np < 0.5f) ? 0.f : (pp - np * (M + __logf(T + 1e-20f))) / np;
        }
#pragma unroll
        for (int off = 32; off >= 1; off >>= 1) mlp += __shfl_xor(mlp, off);
        int lane = t & 63, w = t >> 6;
        if (lane == 0) sh.fin.wsum[w] = mlp;
        __syncthreads();
        if (t == 0) {
            st_agent_f(&wsumv[b],
                       (sh.fin.wsum[0] + sh.fin.wsum[1]) + (sh.fin.wsum[2] + sh.fin.wsum[3]));
            asm volatile("s_waitcnt vmcnt(0)" ::: "memory");   // wsum at MALL before ticket
            int to = fadd_agent(&g_ticket[0]);
            if ((to & 127) == 127) {              // 128th phase-3 block this iteration
                float tot = 0.f;
                for (int j = 0; j < 128; ++j) tot += ld_agent_f(&wsumv[j]);
                double sp = 0.0, sn = 0.0;
                for (int cc = 0; cc < NCLS; ++cc) {
                    double n = (double)sh.fin.cs[cc];
                    sp += n * (n - 1.0);
                    sn += n * ((double)N - n);
                }
                out[0] = (float)(-(0.1 / 0.07) * ((double)tot / (double)N));
                out[1] = (float)(sp / (double)N);
                out[2] = (float)(sn / (double)N);
            }
        }
    }
}

extern "C" void kernel_launch(void* const* d_in, const int* in_sizes, int n_in,
                              void* d_out, int out_size, void* d_ws, size_t ws_size,
                              hipStream_t stream) {
    const float* F = (const float*)d_in[0];
    const int* tgt = (const int*)d_in[1];
    float* out = (float*)d_out;
    char* ws = (char*)d_ws;

    // ws buffers: all written-before-read every iteration -> no memset needed.
    float* wsumv = (float*)(ws + 4096);          // 128 per-block loss sums
    float* PS = (float*)(ws + 98304);            // 32 KiB (zeroed in phase 1a)
    int* Dpart = (int*)(ws + 131072);            // 2 KiB (per-16-row diag mins)
    float* diag10 = (float*)(ws + 163840);       // 32 KiB
    int* Q = (int*)(ws + (1u << 20));            // 1 MiB (i8 frags of 30*F)

    k_fused<<<GRID, TPB, 0, stream>>>(F, tgt, diag10, Q, PS, Dpart, wsumv, out);
}